// Round 2
// baseline (1108.635 us; speedup 1.0000x reference)
//
#include <hip/hip_runtime.h>
#include <cstdint>
#include <cstddef>

// ---------------- init: zero cnt, cursor, g ----------------
__global__ void k_init(int* cnt, int* cursor, float* g, int M, int GH) {
  int i = blockIdx.x * blockDim.x + threadIdx.x;
  int stride = gridDim.x * blockDim.x;
  for (int x = i; x < M; x += stride) { cnt[x] = 0; cursor[x] = 0; }
  for (int x = i; x < GH; x += stride) g[x] = 0.f;
}

// ---------------- degree histogram (incoming edges) ----------------
__global__ void k_count(const int* __restrict__ dst, int* __restrict__ cnt, int E) {
  int i = blockIdx.x * blockDim.x + threadIdx.x;
  for (int e = i; e < E; e += gridDim.x * blockDim.x)
    atomicAdd(&cnt[dst[e]], 1);
}

__global__ void k_dinv(const int* __restrict__ cnt, float* __restrict__ dinv, int M) {
  int i = blockIdx.x * blockDim.x + threadIdx.x;
  if (i < M) dinv[i] = rsqrtf((float)(cnt[i] + 1));  // +1 self loop
}

// ---------------- 2-level exclusive scan over cnt -> row_ptr ----------------
__global__ void k_scan1(const int* __restrict__ cnt, int* __restrict__ excl,
                        int* __restrict__ bsum, int M) {
  __shared__ int s[256];
  int gid = blockIdx.x * 256 + threadIdx.x;
  int v = (gid < M) ? cnt[gid] : 0;
  s[threadIdx.x] = v;
  __syncthreads();
  for (int off = 1; off < 256; off <<= 1) {
    int t = (threadIdx.x >= off) ? s[threadIdx.x - off] : 0;
    __syncthreads();
    s[threadIdx.x] += t;
    __syncthreads();
  }
  if (gid < M) excl[gid] = s[threadIdx.x] - v;
  if (threadIdx.x == 255) bsum[blockIdx.x] = s[255];
}

__global__ void k_scan2(int* bsum, int nb) {
  __shared__ int s[256];
  int v = (threadIdx.x < nb) ? bsum[threadIdx.x] : 0;
  s[threadIdx.x] = v;
  __syncthreads();
  for (int off = 1; off < 256; off <<= 1) {
    int t = (threadIdx.x >= off) ? s[threadIdx.x - off] : 0;
    __syncthreads();
    s[threadIdx.x] += t;
    __syncthreads();
  }
  if (threadIdx.x < nb) bsum[threadIdx.x] = s[threadIdx.x] - v;  // exclusive
}

__global__ void k_scan3(int* row_ptr, const int* __restrict__ bsum, int M, int E) {
  int gid = blockIdx.x * 256 + threadIdx.x;
  if (gid < M) row_ptr[gid] += bsum[blockIdx.x];
  if (gid == 0) row_ptr[M] = E;
}

// ---------------- CSR scatter (by dst) ----------------
__global__ void k_scatter(const int* __restrict__ src, const int* __restrict__ dst,
                          const int* __restrict__ row_ptr, int* __restrict__ cursor,
                          int* __restrict__ eidx, int E) {
  int i = blockIdx.x * blockDim.x + threadIdx.x;
  for (int e = i; e < E; e += gridDim.x * blockDim.x) {
    int d = dst[e];
    int pos = atomicAdd(&cursor[d], 1);
    eidx[row_ptr[d] + pos] = src[e];
  }
}

// ---------------- f32 GEMM: out[r, :256] = (A[r,:K] @ W[K,256]) * dinv[r] ----------------
#define GBK 16
__global__ __launch_bounds__(256) void k_gemm(const float* __restrict__ A,
                                              const float* __restrict__ W,
                                              const float* __restrict__ dinv,
                                              float* __restrict__ out, int M, int K) {
  __shared__ float As[GBK][64 + 1];  // [k][m], padded
  __shared__ float Bs[GBK][64];      // [k][n]
  int tx = threadIdx.x % 16;  // col group (x4)
  int ty = threadIdx.x / 16;  // row group (x4)
  int row0 = blockIdx.x * 64;
  int col0 = blockIdx.y * 64;
  float acc[4][4] = {};
  for (int k0 = 0; k0 < K; k0 += GBK) {
    for (int t = threadIdx.x; t < 64 * GBK; t += 256) {
      int m = t / GBK, k = t % GBK;
      int r = row0 + m;
      As[k][m] = (r < M) ? A[(size_t)r * K + k0 + k] : 0.f;
    }
    for (int t = threadIdx.x; t < GBK * 64; t += 256) {
      int k = t / 64, n = t % 64;
      Bs[k][n] = W[(size_t)(k0 + k) * 256 + col0 + n];
    }
    __syncthreads();
#pragma unroll
    for (int kk = 0; kk < GBK; ++kk) {
      float a[4], b[4];
#pragma unroll
      for (int i = 0; i < 4; i++) a[i] = As[kk][ty * 4 + i];
#pragma unroll
      for (int j = 0; j < 4; j++) b[j] = Bs[kk][tx * 4 + j];
#pragma unroll
      for (int i = 0; i < 4; i++)
#pragma unroll
        for (int j = 0; j < 4; j++) acc[i][j] += a[i] * b[j];
    }
    __syncthreads();
  }
#pragma unroll
  for (int i = 0; i < 4; i++) {
    int r = row0 + ty * 4 + i;
    if (r < M) {
      float s = dinv[r];
#pragma unroll
      for (int j = 0; j < 4; j++)
        out[(size_t)r * 256 + col0 + tx * 4 + j] = acc[i][j] * s;
    }
  }
}

// ---------------- aggregate: out[i] = relu(dinv[i]*(hws[i] + sum_{e:dst=i} hws[src]) + b) ----------------
__global__ __launch_bounds__(64) void k_aggregate(const float* __restrict__ hws,
                                                  const int* __restrict__ eidx,
                                                  const int* __restrict__ row_ptr,
                                                  const float* __restrict__ dinv,
                                                  const float* __restrict__ bias,
                                                  float* __restrict__ out, int M) {
  int i = blockIdx.x;
  if (i >= M) return;
  int t = threadIdx.x;  // 64 threads x float4 = 256 feats
  float4 acc = *(const float4*)(hws + (size_t)i * 256 + t * 4);  // self loop
  int beg = row_ptr[i], end = row_ptr[i + 1];
  for (int e = beg; e < end; ++e) {
    int s = eidx[e];
    float4 v = *(const float4*)(hws + (size_t)s * 256 + t * 4);
    acc.x += v.x; acc.y += v.y; acc.z += v.z; acc.w += v.w;
  }
  float d = dinv[i];
  float4 b = *(const float4*)(bias + t * 4);
  float4 r;
  r.x = fmaxf(fmaf(acc.x, d, b.x), 0.f);
  r.y = fmaxf(fmaf(acc.y, d, b.y), 0.f);
  r.z = fmaxf(fmaf(acc.z, d, b.z), 0.f);
  r.w = fmaxf(fmaf(acc.w, d, b.w), 0.f);
  *(float4*)(out + (size_t)i * 256 + t * 4) = r;
}

// ---------------- segment max pool (batch sorted) ----------------
__global__ __launch_bounds__(256) void k_pool(const float* __restrict__ h,
                                              const int* __restrict__ batch,
                                              float* __restrict__ g, int M) {
  int node0 = blockIdx.x * 32;
  if (node0 >= M) return;
  int t = threadIdx.x;
  int nEnd = min(node0 + 32, M);
  int cur = batch[node0];
  float acc = 0.f;  // post-relu values >= 0
  for (int n = node0; n < nEnd; ++n) {
    int b = batch[n];
    if (b != cur) {
      atomicMax((int*)&g[(size_t)cur * 256 + t], __float_as_int(acc));
      acc = 0.f; cur = b;
    }
    acc = fmaxf(acc, h[(size_t)n * 256 + t]);
  }
  atomicMax((int*)&g[(size_t)cur * 256 + t], __float_as_int(acc));
}

// ---------------- classifier: log_softmax(g @ Wl + bl) ----------------
__global__ __launch_bounds__(256) void k_classify(const float* __restrict__ g,
                                                  const float* __restrict__ Wl,
                                                  const float* __restrict__ bl,
                                                  float* __restrict__ out) {
  __shared__ float sg[256];
  __shared__ float logits[10];
  int b = blockIdx.x;
  sg[threadIdx.x] = g[(size_t)b * 256 + threadIdx.x];
  __syncthreads();
  if (threadIdx.x < 10) {
    float s = bl[threadIdx.x];
    for (int k = 0; k < 256; ++k) s = fmaf(sg[k], Wl[k * 10 + threadIdx.x], s);
    logits[threadIdx.x] = s;
  }
  __syncthreads();
  if (threadIdx.x == 0) {
    float m = logits[0];
    for (int c = 1; c < 10; c++) m = fmaxf(m, logits[c]);
    float sum = 0.f;
    for (int c = 0; c < 10; c++) sum += expf(logits[c] - m);
    float lse = m + logf(sum);
    for (int c = 0; c < 10; c++) out[b * 10 + c] = logits[c] - lse;
  }
}

static inline size_t align256(size_t x) { return (x + 255) & ~(size_t)255; }

extern "C" void kernel_launch(void* const* d_in, const int* in_sizes, int n_in,
                              void* d_out, int out_size, void* d_ws, size_t ws_size,
                              hipStream_t stream) {
  const float* x   = (const float*)d_in[0];
  const int*   ei  = (const int*)d_in[1];
  const int*   bat = (const int*)d_in[2];
  const float* W1  = (const float*)d_in[3];
  const float* b1  = (const float*)d_in[4];
  const float* W2  = (const float*)d_in[5];
  const float* b2  = (const float*)d_in[6];
  const float* W3  = (const float*)d_in[7];
  const float* b3  = (const float*)d_in[8];
  const float* Wl  = (const float*)d_in[9];
  const float* bl  = (const float*)d_in[10];
  float* out = (float*)d_out;

  const int M = in_sizes[0] / 512;  // 50000
  const int E = in_sizes[1] / 2;    // 800000
  const int G = out_size / 10;      // 64

  const int* src = ei;
  const int* dst = ei + E;

  char* p = (char*)d_ws;
  size_t off = 0;
  float* p_dinv = (float*)(p + off); off = align256(off + (size_t)M * 4);
  int* cnt      = (int*)(p + off);   off = align256(off + (size_t)M * 4);
  int* cursor   = (int*)(p + off);   off = align256(off + (size_t)M * 4);
  int* row_ptr  = (int*)(p + off);   off = align256(off + ((size_t)M + 1) * 4);
  int* bsum     = (int*)(p + off);   off = align256(off + 256 * 4);
  int* eidx     = (int*)(p + off);   off = align256(off + (size_t)E * 4);
  float* g      = (float*)(p + off); off = align256(off + (size_t)G * 256 * 4);
  float* bufA   = (float*)(p + off); off = align256(off + (size_t)M * 256 * 4);
  float* bufB   = (float*)(p + off); off = align256(off + (size_t)M * 256 * 4);
  (void)ws_size;

  int nb = (M + 255) / 256;

  k_init<<<256, 256, 0, stream>>>(cnt, cursor, g, M, G * 256);
  k_count<<<1024, 256, 0, stream>>>(dst, cnt, E);
  k_dinv<<<nb, 256, 0, stream>>>(cnt, p_dinv, M);
  k_scan1<<<nb, 256, 0, stream>>>(cnt, row_ptr, bsum, M);
  k_scan2<<<1, 256, 0, stream>>>(bsum, nb);
  k_scan3<<<nb, 256, 0, stream>>>(row_ptr, bsum, M, E);
  k_scatter<<<1024, 256, 0, stream>>>(src, dst, row_ptr, cursor, eidx, E);

  dim3 ggrid((M + 63) / 64, 4);
  // layer 1
  k_gemm<<<ggrid, 256, 0, stream>>>(x, W1, p_dinv, bufA, M, 512);
  k_aggregate<<<M, 64, 0, stream>>>(bufA, eidx, row_ptr, p_dinv, b1, bufB, M);
  // layer 2
  k_gemm<<<ggrid, 256, 0, stream>>>(bufB, W2, p_dinv, bufA, M, 256);
  k_aggregate<<<M, 64, 0, stream>>>(bufA, eidx, row_ptr, p_dinv, b2, bufB, M);
  // layer 3
  k_gemm<<<ggrid, 256, 0, stream>>>(bufB, W3, p_dinv, bufA, M, 256);
  k_aggregate<<<M, 64, 0, stream>>>(bufA, eidx, row_ptr, p_dinv, b3, bufB, M);

  k_pool<<<(M + 31) / 32, 256, 0, stream>>>(bufB, bat, g, M);
  k_classify<<<G, 256, 0, stream>>>(g, Wl, bl, out);
}

// Round 3
// 774.487 us; speedup vs baseline: 1.4314x; 1.4314x over previous
//
#include <hip/hip_runtime.h>
#include <hip/hip_bf16.h>
#include <cstdint>
#include <cstddef>

typedef __attribute__((ext_vector_type(8))) short short8;
typedef __attribute__((ext_vector_type(4))) float f32x4;

// ---- bf16 split helpers (pure bit ops, RN) ----
__device__ __forceinline__ unsigned short f32_to_bf16_rn(float f) {
  unsigned int u = __float_as_uint(f);
  u += 0x7FFFu + ((u >> 16) & 1u);
  return (unsigned short)(u >> 16);
}
__device__ __forceinline__ float bf16_to_f32(unsigned short b) {
  return __uint_as_float(((unsigned int)b) << 16);
}
__device__ __forceinline__ void split_bf(float f, unsigned short& hi, unsigned short& lo) {
  hi = f32_to_bf16_rn(f);
  lo = f32_to_bf16_rn(f - bf16_to_f32(hi));
}

// ---------------- init: zero cnt, cursor, g ----------------
__global__ void k_init(int* cnt, int* cursor, float* g, int M, int GH) {
  int i = blockIdx.x * blockDim.x + threadIdx.x;
  int stride = gridDim.x * blockDim.x;
  for (int x = i; x < M; x += stride) { cnt[x] = 0; cursor[x] = 0; }
  for (int x = i; x < GH; x += stride) g[x] = 0.f;
}

// ---------------- degree histogram (incoming edges) ----------------
__global__ void k_count(const int* __restrict__ dst, int* __restrict__ cnt, int E) {
  int i = blockIdx.x * blockDim.x + threadIdx.x;
  for (int e = i; e < E; e += gridDim.x * blockDim.x)
    atomicAdd(&cnt[dst[e]], 1);
}

__global__ void k_dinv(const int* __restrict__ cnt, float* __restrict__ dinv, int M) {
  int i = blockIdx.x * blockDim.x + threadIdx.x;
  if (i < M) dinv[i] = rsqrtf((float)(cnt[i] + 1));  // +1 self loop
}

// ---------------- 2-level exclusive scan over cnt -> row_ptr ----------------
__global__ void k_scan1(const int* __restrict__ cnt, int* __restrict__ excl,
                        int* __restrict__ bsum, int M) {
  __shared__ int s[256];
  int gid = blockIdx.x * 256 + threadIdx.x;
  int v = (gid < M) ? cnt[gid] : 0;
  s[threadIdx.x] = v;
  __syncthreads();
  for (int off = 1; off < 256; off <<= 1) {
    int t = (threadIdx.x >= off) ? s[threadIdx.x - off] : 0;
    __syncthreads();
    s[threadIdx.x] += t;
    __syncthreads();
  }
  if (gid < M) excl[gid] = s[threadIdx.x] - v;
  if (threadIdx.x == 255) bsum[blockIdx.x] = s[255];
}

__global__ void k_scan2(int* bsum, int nb) {
  __shared__ int s[256];
  int v = (threadIdx.x < nb) ? bsum[threadIdx.x] : 0;
  s[threadIdx.x] = v;
  __syncthreads();
  for (int off = 1; off < 256; off <<= 1) {
    int t = (threadIdx.x >= off) ? s[threadIdx.x - off] : 0;
    __syncthreads();
    s[threadIdx.x] += t;
    __syncthreads();
  }
  if (threadIdx.x < nb) bsum[threadIdx.x] = s[threadIdx.x] - v;  // exclusive
}

__global__ void k_scan3(int* row_ptr, const int* __restrict__ bsum, int M, int E) {
  int gid = blockIdx.x * 256 + threadIdx.x;
  if (gid < M) row_ptr[gid] += bsum[blockIdx.x];
  if (gid == 0) row_ptr[M] = E;
}

// ---------------- CSR scatter (by dst) ----------------
__global__ void k_scatter(const int* __restrict__ src, const int* __restrict__ dst,
                          const int* __restrict__ row_ptr, int* __restrict__ cursor,
                          int* __restrict__ eidx, int E) {
  int i = blockIdx.x * blockDim.x + threadIdx.x;
  for (int e = i; e < E; e += gridDim.x * blockDim.x) {
    int d = dst[e];
    int pos = atomicAdd(&cursor[d], 1);
    eidx[row_ptr[d] + pos] = src[e];
  }
}

// ---------------- W transpose + split: W[K][256] f32 -> WT_hi/lo[256][K] bf16 ----------------
__global__ void k_wtrans(const float* __restrict__ W, unsigned short* __restrict__ WTh,
                         unsigned short* __restrict__ WTl, int K) {
  int idx = blockIdx.x * 256 + threadIdx.x;
  if (idx >= K * 256) return;
  int n = idx / K, k = idx % K;  // writes coalesced in k
  float v = W[(size_t)k * 256 + n];
  unsigned short h, l;
  split_bf(v, h, l);
  WTh[(size_t)n * K + k] = h;
  WTl[(size_t)n * K + k] = l;
}

// ---------------- split-bf16 MFMA GEMM ----------------
// out[r, 0:256] = (A[r,0:K] @ W[0:K,0:256]) * dinv[r]
// A given either as f32 (AF32) or as pre-split hi/lo bf16.
#define BM 64
#define BN 256
#define BK 32

__device__ __forceinline__ int swz(int row, int k) {
  // XOR-swizzle 16B chunks within each row (4 chunks of 8 bf16) to break
  // the 64B-stride bank aliasing on ds_read_b128 / ds_write_b128.
  return row * BK + (((((k >> 3) ^ (row >> 1)) & 3) << 3) | (k & 7));
}

template <bool AF32>
__global__ __launch_bounds__(256) void k_gemm(
    const float* __restrict__ Af,
    const unsigned short* __restrict__ Ahg, const unsigned short* __restrict__ Alg,
    const unsigned short* __restrict__ WTh, const unsigned short* __restrict__ WTl,
    const float* __restrict__ dinv, float* __restrict__ out, int M, int K) {
  __shared__ __align__(16) unsigned short Ah[BM * BK], Al[BM * BK];
  __shared__ __align__(16) unsigned short Bh[BN * BK], Bl[BN * BK];
  const int tid = threadIdx.x;
  const int lane = tid & 63;
  const int wv = tid >> 6;  // wave -> col block wv*64
  const int row0 = blockIdx.x * BM;

  f32x4 acc[4][4] = {};  // [m][n]

  const int arow = tid >> 2;  // staging row 0..63
  const int achk = tid & 3;   // 16B chunk

  for (int k0 = 0; k0 < K; k0 += BK) {
    // ---- stage A (64 x 32) ----
    {
      int gr = row0 + arow;
      int off = swz(arow, achk * 8);
      if constexpr (AF32) {
        float f[8];
        if (gr < M) {
          const float* p = Af + (size_t)gr * K + k0 + achk * 8;
          float4 v0 = *(const float4*)p;
          float4 v1 = *(const float4*)(p + 4);
          f[0] = v0.x; f[1] = v0.y; f[2] = v0.z; f[3] = v0.w;
          f[4] = v1.x; f[5] = v1.y; f[6] = v1.z; f[7] = v1.w;
        } else {
#pragma unroll
          for (int i = 0; i < 8; i++) f[i] = 0.f;
        }
        short8 hv, lv;
#pragma unroll
        for (int i = 0; i < 8; i++) {
          unsigned short h, l;
          split_bf(f[i], h, l);
          hv[i] = (short)h; lv[i] = (short)l;
        }
        *(short8*)&Ah[off] = hv;
        *(short8*)&Al[off] = lv;
      } else {
        short8 vh, vl;
        if (gr < M) {
          vh = *(const short8*)(Ahg + (size_t)gr * K + k0 + achk * 8);
          vl = *(const short8*)(Alg + (size_t)gr * K + k0 + achk * 8);
        } else {
          vh = (short8)(short)0; vl = (short8)(short)0;
        }
        *(short8*)&Ah[off] = vh;
        *(short8*)&Al[off] = vl;
      }
    }
    // ---- stage B (256 x 32) from WT[col][k] ----
#pragma unroll
    for (int it = 0; it < 4; ++it) {
      int idx = tid + it * 256;
      int col = idx >> 2, chk = idx & 3;
      short8 vh = *(const short8*)(WTh + (size_t)col * K + k0 + chk * 8);
      short8 vl = *(const short8*)(WTl + (size_t)col * K + k0 + chk * 8);
      int off = swz(col, chk * 8);
      *(short8*)&Bh[off] = vh;
      *(short8*)&Bl[off] = vl;
    }
    __syncthreads();
    // ---- fragments + MFMA (3 per pair: hh + hl + lh) ----
    const int fr = lane & 15;
    const int kq = (lane >> 4) * 8;
    short8 ah[4], al[4];
#pragma unroll
    for (int m = 0; m < 4; ++m) {
      int off = swz(m * 16 + fr, kq);
      ah[m] = *(const short8*)&Ah[off];
      al[m] = *(const short8*)&Al[off];
    }
#pragma unroll
    for (int n = 0; n < 4; ++n) {
      int off = swz(wv * 64 + n * 16 + fr, kq);
      short8 bh = *(const short8*)&Bh[off];
      short8 bl = *(const short8*)&Bl[off];
#pragma unroll
      for (int m = 0; m < 4; ++m) {
        acc[m][n] = __builtin_amdgcn_mfma_f32_16x16x32_bf16(ah[m], bh, acc[m][n], 0, 0, 0);
        acc[m][n] = __builtin_amdgcn_mfma_f32_16x16x32_bf16(ah[m], bl, acc[m][n], 0, 0, 0);
        acc[m][n] = __builtin_amdgcn_mfma_f32_16x16x32_bf16(al[m], bh, acc[m][n], 0, 0, 0);
      }
    }
    __syncthreads();
  }
  // ---- epilogue: C/D layout col=lane&15, row=(lane>>4)*4+reg (m89-verified) ----
  const int fr = lane & 15;
  const int rq = (lane >> 4) * 4;
#pragma unroll
  for (int m = 0; m < 4; ++m) {
#pragma unroll
    for (int r = 0; r < 4; ++r) {
      int gr = row0 + m * 16 + rq + r;
      if (gr < M) {
        float s = dinv[gr];
#pragma unroll
        for (int n = 0; n < 4; ++n)
          out[(size_t)gr * BN + wv * 64 + n * 16 + fr] = acc[m][n][r] * s;
      }
    }
  }
}

// ---------------- aggregate: h[i] = relu(dinv[i]*(hws[i] + sum_{e:dst=i} hws[src]) + b)
// writes hi/lo bf16 (GEMM input) OR f32 (pool input) ----------------
__global__ __launch_bounds__(64) void k_aggregate(
    const float* __restrict__ hws, const int* __restrict__ eidx,
    const int* __restrict__ row_ptr, const float* __restrict__ dinv,
    const float* __restrict__ bias, unsigned short* __restrict__ out_hi,
    unsigned short* __restrict__ out_lo, float* __restrict__ out_f32, int M) {
  int i = blockIdx.x;
  if (i >= M) return;
  int t = threadIdx.x;  // 64 threads x float4 = 256 feats
  float4 acc = *(const float4*)(hws + (size_t)i * 256 + t * 4);  // self loop
  int beg = row_ptr[i], end = row_ptr[i + 1];
  for (int e = beg; e < end; ++e) {
    int s = eidx[e];
    float4 v = *(const float4*)(hws + (size_t)s * 256 + t * 4);
    acc.x += v.x; acc.y += v.y; acc.z += v.z; acc.w += v.w;
  }
  float d = dinv[i];
  float4 b = *(const float4*)(bias + t * 4);
  float r[4];
  r[0] = fmaxf(fmaf(acc.x, d, b.x), 0.f);
  r[1] = fmaxf(fmaf(acc.y, d, b.y), 0.f);
  r[2] = fmaxf(fmaf(acc.z, d, b.z), 0.f);
  r[3] = fmaxf(fmaf(acc.w, d, b.w), 0.f);
  if (out_f32) {
    float4 o; o.x = r[0]; o.y = r[1]; o.z = r[2]; o.w = r[3];
    *(float4*)(out_f32 + (size_t)i * 256 + t * 4) = o;
  } else {
    ushort4 hv, lv;
    unsigned short h, l;
    split_bf(r[0], h, l); hv.x = h; lv.x = l;
    split_bf(r[1], h, l); hv.y = h; lv.y = l;
    split_bf(r[2], h, l); hv.z = h; lv.z = l;
    split_bf(r[3], h, l); hv.w = h; lv.w = l;
    *(ushort4*)(out_hi + (size_t)i * 256 + t * 4) = hv;
    *(ushort4*)(out_lo + (size_t)i * 256 + t * 4) = lv;
  }
}

// ---------------- segment max pool (batch sorted) ----------------
__global__ __launch_bounds__(256) void k_pool(const float* __restrict__ h,
                                              const int* __restrict__ batch,
                                              float* __restrict__ g, int M) {
  int node0 = blockIdx.x * 32;
  if (node0 >= M) return;
  int t = threadIdx.x;
  int nEnd = min(node0 + 32, M);
  int cur = batch[node0];
  float acc = 0.f;  // post-relu values >= 0
  for (int n = node0; n < nEnd; ++n) {
    int b = batch[n];
    if (b != cur) {
      atomicMax((int*)&g[(size_t)cur * 256 + t], __float_as_int(acc));
      acc = 0.f; cur = b;
    }
    acc = fmaxf(acc, h[(size_t)n * 256 + t]);
  }
  atomicMax((int*)&g[(size_t)cur * 256 + t], __float_as_int(acc));
}

// ---------------- classifier: log_softmax(g @ Wl + bl) ----------------
__global__ __launch_bounds__(256) void k_classify(const float* __restrict__ g,
                                                  const float* __restrict__ Wl,
                                                  const float* __restrict__ bl,
                                                  float* __restrict__ out) {
  __shared__ float sg[256];
  __shared__ float logits[10];
  int b = blockIdx.x;
  sg[threadIdx.x] = g[(size_t)b * 256 + threadIdx.x];
  __syncthreads();
  if (threadIdx.x < 10) {
    float s = bl[threadIdx.x];
    for (int k = 0; k < 256; ++k) s = fmaf(sg[k], Wl[k * 10 + threadIdx.x], s);
    logits[threadIdx.x] = s;
  }
  __syncthreads();
  if (threadIdx.x == 0) {
    float m = logits[0];
    for (int c = 1; c < 10; c++) m = fmaxf(m, logits[c]);
    float sum = 0.f;
    for (int c = 0; c < 10; c++) sum += expf(logits[c] - m);
    float lse = m + logf(sum);
    for (int c = 0; c < 10; c++) out[b * 10 + c] = logits[c] - lse;
  }
}

static inline size_t align256(size_t x) { return (x + 255) & ~(size_t)255; }

extern "C" void kernel_launch(void* const* d_in, const int* in_sizes, int n_in,
                              void* d_out, int out_size, void* d_ws, size_t ws_size,
                              hipStream_t stream) {
  const float* x   = (const float*)d_in[0];
  const int*   ei  = (const int*)d_in[1];
  const int*   bat = (const int*)d_in[2];
  const float* W1  = (const float*)d_in[3];
  const float* b1  = (const float*)d_in[4];
  const float* W2  = (const float*)d_in[5];
  const float* b2  = (const float*)d_in[6];
  const float* W3  = (const float*)d_in[7];
  const float* b3  = (const float*)d_in[8];
  const float* Wl  = (const float*)d_in[9];
  const float* bl  = (const float*)d_in[10];
  float* out = (float*)d_out;

  const int M = in_sizes[0] / 512;  // 50000
  const int E = in_sizes[1] / 2;    // 800000
  const int G = out_size / 10;      // 64
  const int K1 = 512, H = 256;

  const int* src = ei;
  const int* dst = ei + E;

  char* p = (char*)d_ws;
  size_t off = 0;
  float* p_dinv = (float*)(p + off); off = align256(off + (size_t)M * 4);
  int* cnt      = (int*)(p + off);   off = align256(off + (size_t)M * 4);
  int* cursor   = (int*)(p + off);   off = align256(off + (size_t)M * 4);
  int* row_ptr  = (int*)(p + off);   off = align256(off + ((size_t)M + 1) * 4);
  int* bsum     = (int*)(p + off);   off = align256(off + 256 * 4);
  int* eidx     = (int*)(p + off);   off = align256(off + (size_t)E * 4);
  float* g      = (float*)(p + off); off = align256(off + (size_t)G * H * 4);
  unsigned short* WT1h = (unsigned short*)(p + off); off = align256(off + (size_t)H * K1 * 2);
  unsigned short* WT1l = (unsigned short*)(p + off); off = align256(off + (size_t)H * K1 * 2);
  unsigned short* WT2h = (unsigned short*)(p + off); off = align256(off + (size_t)H * H * 2);
  unsigned short* WT2l = (unsigned short*)(p + off); off = align256(off + (size_t)H * H * 2);
  unsigned short* WT3h = (unsigned short*)(p + off); off = align256(off + (size_t)H * H * 2);
  unsigned short* WT3l = (unsigned short*)(p + off); off = align256(off + (size_t)H * H * 2);
  float* hws    = (float*)(p + off); off = align256(off + (size_t)M * H * 4);
  unsigned short* h_hi = (unsigned short*)(p + off); off += (size_t)M * H * 2;  // no pad:
  unsigned short* h_lo = (unsigned short*)(p + off); off = align256(off + (size_t)M * H * 2);
  float* bufC = (float*)h_hi;  // layer-3 f32 output aliases h_hi+h_lo (both dead by then)
  (void)ws_size;

  int nb = (M + 255) / 256;

  k_init<<<256, 256, 0, stream>>>(cnt, cursor, g, M, G * H);
  k_count<<<1024, 256, 0, stream>>>(dst, cnt, E);
  k_dinv<<<nb, 256, 0, stream>>>(cnt, p_dinv, M);
  k_scan1<<<nb, 256, 0, stream>>>(cnt, row_ptr, bsum, M);
  k_scan2<<<1, 256, 0, stream>>>(bsum, nb);
  k_scan3<<<nb, 256, 0, stream>>>(row_ptr, bsum, M, E);
  k_scatter<<<1024, 256, 0, stream>>>(src, dst, row_ptr, cursor, eidx, E);

  k_wtrans<<<(H * K1 + 255) / 256, 256, 0, stream>>>(W1, WT1h, WT1l, K1);
  k_wtrans<<<(H * H + 255) / 256, 256, 0, stream>>>(W2, WT2h, WT2l, H);
  k_wtrans<<<(H * H + 255) / 256, 256, 0, stream>>>(W3, WT3h, WT3l, H);

  int gblk = (M + BM - 1) / BM;
  // layer 1 (A = x, f32, K=512)
  k_gemm<true><<<gblk, 256, 0, stream>>>(x, nullptr, nullptr, WT1h, WT1l, p_dinv, hws, M, K1);
  k_aggregate<<<M, 64, 0, stream>>>(hws, eidx, row_ptr, p_dinv, b1, h_hi, h_lo, nullptr, M);
  // layer 2 (A = h hi/lo, K=256)
  k_gemm<false><<<gblk, 256, 0, stream>>>(nullptr, h_hi, h_lo, WT2h, WT2l, p_dinv, hws, M, H);
  k_aggregate<<<M, 64, 0, stream>>>(hws, eidx, row_ptr, p_dinv, b2, h_hi, h_lo, nullptr, M);
  // layer 3 -> f32 for pool
  k_gemm<false><<<gblk, 256, 0, stream>>>(nullptr, h_hi, h_lo, WT3h, WT3l, p_dinv, hws, M, H);
  k_aggregate<<<M, 64, 0, stream>>>(hws, eidx, row_ptr, p_dinv, b3, nullptr, nullptr, bufC, M);

  k_pool<<<(M + 31) / 32, 256, 0, stream>>>(bufC, bat, g, M);
  k_classify<<<G, 256, 0, stream>>>(g, Wl, bl, out);
}

// Round 4
// 587.572 us; speedup vs baseline: 1.8868x; 1.3181x over previous
//
#include <hip/hip_runtime.h>
#include <hip/hip_bf16.h>
#include <cstdint>
#include <cstddef>

typedef __attribute__((ext_vector_type(8))) short short8;
typedef __attribute__((ext_vector_type(4))) float f32x4;

// ---- bf16 split helpers (pure bit ops, RN) ----
__device__ __forceinline__ unsigned short f32_to_bf16_rn(float f) {
  unsigned int u = __float_as_uint(f);
  u += 0x7FFFu + ((u >> 16) & 1u);
  return (unsigned short)(u >> 16);
}
__device__ __forceinline__ float bf16_to_f32(unsigned short b) {
  return __uint_as_float(((unsigned int)b) << 16);
}
__device__ __forceinline__ void split_bf(float f, unsigned short& hi, unsigned short& lo) {
  hi = f32_to_bf16_rn(f);
  lo = f32_to_bf16_rn(f - bf16_to_f32(hi));
}
__device__ __forceinline__ float4 bf4_to_f4(ushort4 v) {
  float4 r;
  r.x = bf16_to_f32(v.x); r.y = bf16_to_f32(v.y);
  r.z = bf16_to_f32(v.z); r.w = bf16_to_f32(v.w);
  return r;
}

// ---------------- init: zero cnt, cursor, g ----------------
__global__ void k_init(int* cnt, int* cursor, float* g, int M, int GH) {
  int i = blockIdx.x * blockDim.x + threadIdx.x;
  int stride = gridDim.x * blockDim.x;
  for (int x = i; x < M; x += stride) { cnt[x] = 0; cursor[x] = 0; }
  for (int x = i; x < GH; x += stride) g[x] = 0.f;
}

// ---------------- degree histogram (incoming edges) ----------------
__global__ void k_count(const int* __restrict__ dst, int* __restrict__ cnt, int E) {
  int i = blockIdx.x * blockDim.x + threadIdx.x;
  for (int e = i; e < E; e += gridDim.x * blockDim.x)
    atomicAdd(&cnt[dst[e]], 1);
}

__global__ void k_dinv(const int* __restrict__ cnt, float* __restrict__ dinv, int M) {
  int i = blockIdx.x * blockDim.x + threadIdx.x;
  if (i < M) dinv[i] = rsqrtf((float)(cnt[i] + 1));  // +1 self loop
}

// ---------------- 2-level exclusive scan over cnt -> row_ptr ----------------
__global__ void k_scan1(const int* __restrict__ cnt, int* __restrict__ excl,
                        int* __restrict__ bsum, int M) {
  __shared__ int s[256];
  int gid = blockIdx.x * 256 + threadIdx.x;
  int v = (gid < M) ? cnt[gid] : 0;
  s[threadIdx.x] = v;
  __syncthreads();
  for (int off = 1; off < 256; off <<= 1) {
    int t = (threadIdx.x >= off) ? s[threadIdx.x - off] : 0;
    __syncthreads();
    s[threadIdx.x] += t;
    __syncthreads();
  }
  if (gid < M) excl[gid] = s[threadIdx.x] - v;
  if (threadIdx.x == 255) bsum[blockIdx.x] = s[255];
}

__global__ void k_scan2(int* bsum, int nb) {
  __shared__ int s[256];
  int v = (threadIdx.x < nb) ? bsum[threadIdx.x] : 0;
  s[threadIdx.x] = v;
  __syncthreads();
  for (int off = 1; off < 256; off <<= 1) {
    int t = (threadIdx.x >= off) ? s[threadIdx.x - off] : 0;
    __syncthreads();
    s[threadIdx.x] += t;
    __syncthreads();
  }
  if (threadIdx.x < nb) bsum[threadIdx.x] = s[threadIdx.x] - v;  // exclusive
}

__global__ void k_scan3(int* row_ptr, const int* __restrict__ bsum, int M, int E) {
  int gid = blockIdx.x * 256 + threadIdx.x;
  if (gid < M) row_ptr[gid] += bsum[blockIdx.x];
  if (gid == 0) row_ptr[M] = E;
}

// ---------------- CSR scatter (by dst) ----------------
__global__ void k_scatter(const int* __restrict__ src, const int* __restrict__ dst,
                          const int* __restrict__ row_ptr, int* __restrict__ cursor,
                          int* __restrict__ eidx, int E) {
  int i = blockIdx.x * blockDim.x + threadIdx.x;
  for (int e = i; e < E; e += gridDim.x * blockDim.x) {
    int d = dst[e];
    int pos = atomicAdd(&cursor[d], 1);
    eidx[row_ptr[d] + pos] = src[e];
  }
}

// ---------------- W transpose + split: W[K][256] f32 -> WT_hi/lo[256][K] bf16 ----------------
__global__ void k_wtrans(const float* __restrict__ W, unsigned short* __restrict__ WTh,
                         unsigned short* __restrict__ WTl, int K) {
  int idx = blockIdx.x * 256 + threadIdx.x;
  if (idx >= K * 256) return;
  int n = idx / K, k = idx % K;  // writes coalesced in k
  float v = W[(size_t)k * 256 + n];
  unsigned short h, l;
  split_bf(v, h, l);
  WTh[(size_t)n * K + k] = h;
  WTl[(size_t)n * K + k] = l;
}

// ---------------- split-bf16 MFMA GEMM ----------------
// outbf[r, 0:256] = bf16( (A[r,0:K] @ W[0:K,0:256]) * dinv[r] )
#define BM 64
#define BN 256
#define BK 32

__device__ __forceinline__ int swz(int row, int k) {
  // XOR-swizzle 16B chunks within each row (4 chunks of 8 bf16) to break
  // the 64B-stride bank aliasing on ds_read_b128 / ds_write_b128.
  return row * BK + (((((k >> 3) ^ (row >> 1)) & 3) << 3) | (k & 7));
}

template <bool AF32>
__global__ __launch_bounds__(256) void k_gemm(
    const float* __restrict__ Af,
    const unsigned short* __restrict__ Ahg, const unsigned short* __restrict__ Alg,
    const unsigned short* __restrict__ WTh, const unsigned short* __restrict__ WTl,
    const float* __restrict__ dinv, unsigned short* __restrict__ out, int M, int K) {
  __shared__ __align__(16) unsigned short Ah[BM * BK], Al[BM * BK];
  __shared__ __align__(16) unsigned short Bh[BN * BK], Bl[BN * BK];
  const int tid = threadIdx.x;
  const int lane = tid & 63;
  const int wv = tid >> 6;  // wave -> col block wv*64
  const int row0 = blockIdx.x * BM;

  f32x4 acc[4][4] = {};  // [m][n]

  const int arow = tid >> 2;  // staging row 0..63
  const int achk = tid & 3;   // 16B chunk

  for (int k0 = 0; k0 < K; k0 += BK) {
    // ---- stage A (64 x 32) ----
    {
      int gr = row0 + arow;
      int off = swz(arow, achk * 8);
      if constexpr (AF32) {
        float f[8];
        if (gr < M) {
          const float* p = Af + (size_t)gr * K + k0 + achk * 8;
          float4 v0 = *(const float4*)p;
          float4 v1 = *(const float4*)(p + 4);
          f[0] = v0.x; f[1] = v0.y; f[2] = v0.z; f[3] = v0.w;
          f[4] = v1.x; f[5] = v1.y; f[6] = v1.z; f[7] = v1.w;
        } else {
#pragma unroll
          for (int i = 0; i < 8; i++) f[i] = 0.f;
        }
        short8 hv, lv;
#pragma unroll
        for (int i = 0; i < 8; i++) {
          unsigned short h, l;
          split_bf(f[i], h, l);
          hv[i] = (short)h; lv[i] = (short)l;
        }
        *(short8*)&Ah[off] = hv;
        *(short8*)&Al[off] = lv;
      } else {
        short8 vh, vl;
        if (gr < M) {
          vh = *(const short8*)(Ahg + (size_t)gr * K + k0 + achk * 8);
          vl = *(const short8*)(Alg + (size_t)gr * K + k0 + achk * 8);
        } else {
          vh = (short8)(short)0; vl = (short8)(short)0;
        }
        *(short8*)&Ah[off] = vh;
        *(short8*)&Al[off] = vl;
      }
    }
    // ---- stage B (256 x 32) from WT[col][k] ----
#pragma unroll
    for (int it = 0; it < 4; ++it) {
      int idx = tid + it * 256;
      int col = idx >> 2, chk = idx & 3;
      short8 vh = *(const short8*)(WTh + (size_t)col * K + k0 + chk * 8);
      short8 vl = *(const short8*)(WTl + (size_t)col * K + k0 + chk * 8);
      int off = swz(col, chk * 8);
      *(short8*)&Bh[off] = vh;
      *(short8*)&Bl[off] = vl;
    }
    __syncthreads();
    // ---- fragments + MFMA (3 per pair: hh + hl + lh) ----
    const int fr = lane & 15;
    const int kq = (lane >> 4) * 8;
    short8 ah[4], al[4];
#pragma unroll
    for (int m = 0; m < 4; ++m) {
      int off = swz(m * 16 + fr, kq);
      ah[m] = *(const short8*)&Ah[off];
      al[m] = *(const short8*)&Al[off];
    }
#pragma unroll
    for (int n = 0; n < 4; ++n) {
      int off = swz(wv * 64 + n * 16 + fr, kq);
      short8 bh = *(const short8*)&Bh[off];
      short8 bl = *(const short8*)&Bl[off];
#pragma unroll
      for (int m = 0; m < 4; ++m) {
        acc[m][n] = __builtin_amdgcn_mfma_f32_16x16x32_bf16(ah[m], bh, acc[m][n], 0, 0, 0);
        acc[m][n] = __builtin_amdgcn_mfma_f32_16x16x32_bf16(ah[m], bl, acc[m][n], 0, 0, 0);
        acc[m][n] = __builtin_amdgcn_mfma_f32_16x16x32_bf16(al[m], bh, acc[m][n], 0, 0, 0);
      }
    }
    __syncthreads();
  }
  // ---- epilogue: C/D layout col=lane&15, row=(lane>>4)*4+reg (m89-verified) ----
  const int fr = lane & 15;
  const int rq = (lane >> 4) * 4;
#pragma unroll
  for (int m = 0; m < 4; ++m) {
#pragma unroll
    for (int r = 0; r < 4; ++r) {
      int gr = row0 + m * 16 + rq + r;
      if (gr < M) {
        float s = dinv[gr];
#pragma unroll
        for (int n = 0; n < 4; ++n)
          out[(size_t)gr * BN + wv * 64 + n * 16 + fr] = f32_to_bf16_rn(acc[m][n][r] * s);
      }
    }
  }
}

// ---------------- aggregate: h[i] = relu(dinv[i]*(hws[i] + sum_{e:dst=i} hws[src]) + b)
// hws is bf16 [M][256]; writes hi/lo bf16 (GEMM input) OR f32 (pool input) --------
__global__ __launch_bounds__(64) void k_aggregate(
    const unsigned short* __restrict__ hws, const int* __restrict__ eidx,
    const int* __restrict__ row_ptr, const float* __restrict__ dinv,
    const float* __restrict__ bias, unsigned short* __restrict__ out_hi,
    unsigned short* __restrict__ out_lo, float* __restrict__ out_f32, int M) {
  int i = blockIdx.x;
  if (i >= M) return;
  int t = threadIdx.x;  // 64 threads x 4 feats = 256
  float4 acc = bf4_to_f4(*(const ushort4*)(hws + (size_t)i * 256 + t * 4));  // self loop
  int beg = row_ptr[i], end = row_ptr[i + 1];
  int e = beg;
  // unroll x4: 4 row-gathers in flight per wave
  for (; e + 4 <= end; e += 4) {
    int s0 = eidx[e + 0], s1 = eidx[e + 1], s2 = eidx[e + 2], s3 = eidx[e + 3];
    ushort4 v0 = *(const ushort4*)(hws + (size_t)s0 * 256 + t * 4);
    ushort4 v1 = *(const ushort4*)(hws + (size_t)s1 * 256 + t * 4);
    ushort4 v2 = *(const ushort4*)(hws + (size_t)s2 * 256 + t * 4);
    ushort4 v3 = *(const ushort4*)(hws + (size_t)s3 * 256 + t * 4);
    float4 f0 = bf4_to_f4(v0), f1 = bf4_to_f4(v1);
    float4 f2 = bf4_to_f4(v2), f3 = bf4_to_f4(v3);
    acc.x += (f0.x + f1.x) + (f2.x + f3.x);
    acc.y += (f0.y + f1.y) + (f2.y + f3.y);
    acc.z += (f0.z + f1.z) + (f2.z + f3.z);
    acc.w += (f0.w + f1.w) + (f2.w + f3.w);
  }
  for (; e < end; ++e) {
    int s = eidx[e];
    float4 v = bf4_to_f4(*(const ushort4*)(hws + (size_t)s * 256 + t * 4));
    acc.x += v.x; acc.y += v.y; acc.z += v.z; acc.w += v.w;
  }
  float d = dinv[i];
  float4 b = *(const float4*)(bias + t * 4);
  float r[4];
  r[0] = fmaxf(fmaf(acc.x, d, b.x), 0.f);
  r[1] = fmaxf(fmaf(acc.y, d, b.y), 0.f);
  r[2] = fmaxf(fmaf(acc.z, d, b.z), 0.f);
  r[3] = fmaxf(fmaf(acc.w, d, b.w), 0.f);
  if (out_f32) {
    float4 o; o.x = r[0]; o.y = r[1]; o.z = r[2]; o.w = r[3];
    *(float4*)(out_f32 + (size_t)i * 256 + t * 4) = o;
  } else {
    ushort4 hv, lv;
    unsigned short h, l;
    split_bf(r[0], h, l); hv.x = h; lv.x = l;
    split_bf(r[1], h, l); hv.y = h; lv.y = l;
    split_bf(r[2], h, l); hv.z = h; lv.z = l;
    split_bf(r[3], h, l); hv.w = h; lv.w = l;
    *(ushort4*)(out_hi + (size_t)i * 256 + t * 4) = hv;
    *(ushort4*)(out_lo + (size_t)i * 256 + t * 4) = lv;
  }
}

// ---------------- segment max pool (batch sorted) ----------------
__global__ __launch_bounds__(256) void k_pool(const float* __restrict__ h,
                                              const int* __restrict__ batch,
                                              float* __restrict__ g, int M) {
  int node0 = blockIdx.x * 32;
  if (node0 >= M) return;
  int t = threadIdx.x;
  int nEnd = min(node0 + 32, M);
  int cur = batch[node0];
  float acc = 0.f;  // post-relu values >= 0
  for (int n = node0; n < nEnd; ++n) {
    int b = batch[n];
    if (b != cur) {
      atomicMax((int*)&g[(size_t)cur * 256 + t], __float_as_int(acc));
      acc = 0.f; cur = b;
    }
    acc = fmaxf(acc, h[(size_t)n * 256 + t]);
  }
  atomicMax((int*)&g[(size_t)cur * 256 + t], __float_as_int(acc));
}

// ---------------- classifier: log_softmax(g @ Wl + bl) ----------------
__global__ __launch_bounds__(256) void k_classify(const float* __restrict__ g,
                                                  const float* __restrict__ Wl,
                                                  const float* __restrict__ bl,
                                                  float* __restrict__ out) {
  __shared__ float sg[256];
  __shared__ float logits[10];
  int b = blockIdx.x;
  sg[threadIdx.x] = g[(size_t)b * 256 + threadIdx.x];
  __syncthreads();
  if (threadIdx.x < 10) {
    float s = bl[threadIdx.x];
    for (int k = 0; k < 256; ++k) s = fmaf(sg[k], Wl[k * 10 + threadIdx.x], s);
    logits[threadIdx.x] = s;
  }
  __syncthreads();
  if (threadIdx.x == 0) {
    float m = logits[0];
    for (int c = 1; c < 10; c++) m = fmaxf(m, logits[c]);
    float sum = 0.f;
    for (int c = 0; c < 10; c++) sum += expf(logits[c] - m);
    float lse = m + logf(sum);
    for (int c = 0; c < 10; c++) out[b * 10 + c] = logits[c] - lse;
  }
}

static inline size_t align256(size_t x) { return (x + 255) & ~(size_t)255; }

extern "C" void kernel_launch(void* const* d_in, const int* in_sizes, int n_in,
                              void* d_out, int out_size, void* d_ws, size_t ws_size,
                              hipStream_t stream) {
  const float* x   = (const float*)d_in[0];
  const int*   ei  = (const int*)d_in[1];
  const int*   bat = (const int*)d_in[2];
  const float* W1  = (const float*)d_in[3];
  const float* b1  = (const float*)d_in[4];
  const float* W2  = (const float*)d_in[5];
  const float* b2  = (const float*)d_in[6];
  const float* W3  = (const float*)d_in[7];
  const float* b3  = (const float*)d_in[8];
  const float* Wl  = (const float*)d_in[9];
  const float* bl  = (const float*)d_in[10];
  float* out = (float*)d_out;

  const int M = in_sizes[0] / 512;  // 50000
  const int E = in_sizes[1] / 2;    // 800000
  const int G = out_size / 10;      // 64
  const int K1 = 512, H = 256;

  const int* src = ei;
  const int* dst = ei + E;

  char* p = (char*)d_ws;
  size_t off = 0;
  float* p_dinv = (float*)(p + off); off = align256(off + (size_t)M * 4);
  int* cnt      = (int*)(p + off);   off = align256(off + (size_t)M * 4);
  int* cursor   = (int*)(p + off);   off = align256(off + (size_t)M * 4);
  int* row_ptr  = (int*)(p + off);   off = align256(off + ((size_t)M + 1) * 4);
  int* bsum     = (int*)(p + off);   off = align256(off + 256 * 4);
  int* eidx     = (int*)(p + off);   off = align256(off + (size_t)E * 4);
  float* g      = (float*)(p + off); off = align256(off + (size_t)G * H * 4);
  unsigned short* WT1h = (unsigned short*)(p + off); off = align256(off + (size_t)H * K1 * 2);
  unsigned short* WT1l = (unsigned short*)(p + off); off = align256(off + (size_t)H * K1 * 2);
  unsigned short* WT2h = (unsigned short*)(p + off); off = align256(off + (size_t)H * H * 2);
  unsigned short* WT2l = (unsigned short*)(p + off); off = align256(off + (size_t)H * H * 2);
  unsigned short* WT3h = (unsigned short*)(p + off); off = align256(off + (size_t)H * H * 2);
  unsigned short* WT3l = (unsigned short*)(p + off); off = align256(off + (size_t)H * H * 2);
  unsigned short* hws = (unsigned short*)(p + off); off = align256(off + (size_t)M * H * 2);
  unsigned short* h_hi = (unsigned short*)(p + off); off += (size_t)M * H * 2;  // no pad:
  unsigned short* h_lo = (unsigned short*)(p + off); off = align256(off + (size_t)M * H * 2);
  float* bufC = (float*)h_hi;  // layer-3 f32 output aliases h_hi+h_lo (both dead by then)
  (void)ws_size;

  int nb = (M + 255) / 256;

  k_init<<<256, 256, 0, stream>>>(cnt, cursor, g, M, G * H);
  k_count<<<1024, 256, 0, stream>>>(dst, cnt, E);
  k_dinv<<<nb, 256, 0, stream>>>(cnt, p_dinv, M);
  k_scan1<<<nb, 256, 0, stream>>>(cnt, row_ptr, bsum, M);
  k_scan2<<<1, 256, 0, stream>>>(bsum, nb);
  k_scan3<<<nb, 256, 0, stream>>>(row_ptr, bsum, M, E);
  k_scatter<<<1024, 256, 0, stream>>>(src, dst, row_ptr, cursor, eidx, E);

  k_wtrans<<<(H * K1 + 255) / 256, 256, 0, stream>>>(W1, WT1h, WT1l, K1);
  k_wtrans<<<(H * H + 255) / 256, 256, 0, stream>>>(W2, WT2h, WT2l, H);
  k_wtrans<<<(H * H + 255) / 256, 256, 0, stream>>>(W3, WT3h, WT3l, H);

  int gblk = (M + BM - 1) / BM;
  // layer 1 (A = x, f32, K=512)
  k_gemm<true><<<gblk, 256, 0, stream>>>(x, nullptr, nullptr, WT1h, WT1l, p_dinv, hws, M, K1);
  k_aggregate<<<M, 64, 0, stream>>>(hws, eidx, row_ptr, p_dinv, b1, h_hi, h_lo, nullptr, M);
  // layer 2 (A = h hi/lo, K=256)
  k_gemm<false><<<gblk, 256, 0, stream>>>(nullptr, h_hi, h_lo, WT2h, WT2l, p_dinv, hws, M, H);
  k_aggregate<<<M, 64, 0, stream>>>(hws, eidx, row_ptr, p_dinv, b2, h_hi, h_lo, nullptr, M);
  // layer 3 -> f32 for pool
  k_gemm<false><<<gblk, 256, 0, stream>>>(nullptr, h_hi, h_lo, WT3h, WT3l, p_dinv, hws, M, H);
  k_aggregate<<<M, 64, 0, stream>>>(hws, eidx, row_ptr, p_dinv, b3, nullptr, nullptr, bufC, M);

  k_pool<<<(M + 31) / 32, 256, 0, stream>>>(bufC, bat, g, M);
  k_classify<<<G, 256, 0, stream>>>(g, Wl, bl, out);
}